// Round 16
// baseline (210580.957 us; speedup 1.0000x reference)
//
#include <hip/hip_runtime.h>
#include <hip/hip_bf16.h>
#include <hip/hip_cooperative_groups.h>
#include <stdint.h>
#include <stddef.h>

// ============================================================================
// ROUND 16: persistent cooperative kernel. R15 = 171 us/step vs ~31 us/step
// fp32-VALU floor; residual is inter-kernel overhead (1602 dependent
// dispatches x launch+drain+cold-start). One cooperative kernel, t-loop
// inside, grid.sync() x4/step. Grid 256 blocks (1/CU) x 512 threads,
// LDS union 61KB. Phases: A gates-att (all), B attention (64), C gates-dec
// (all), D outphase+prenet (64).
// ============================================================================
#define SPLIT_MODE 0
#define BITS_MODE  0
#define KSPLIT 8

#define B_    64
#define TIN   200
#define TOUT  400
#define ENC   512
#define NMEL  80
#define PRE   256
#define RNN   1024
#define G4    4096
#define ATTD  128
#define LOCF  32
#define LOCK  31
#define MSIZE 6569984u   // 401*64*256
#define WSTR  132

namespace cg = cooperative_groups;

// ---------------- threefry2x32-20 (hand-verified vs split(PRNGKey(0))) ----------------
__host__ __device__ inline void tf2x32(uint32_t k0, uint32_t k1, uint32_t x0, uint32_t x1,
                                       uint32_t* o0, uint32_t* o1) {
  uint32_t k2 = k0 ^ k1 ^ 0x1BD11BDAu;
#define TFROT(v, r) (((v) << (r)) | ((v) >> (32 - (r))))
#define TFR(r) { x0 += x1; x1 = TFROT(x1, r); x1 ^= x0; }
  x0 += k0; x1 += k1;
  TFR(13) TFR(15) TFR(26) TFR(6)  x0 += k1; x1 += k2 + 1u;
  TFR(17) TFR(29) TFR(16) TFR(24) x0 += k2; x1 += k0 + 2u;
  TFR(13) TFR(15) TFR(26) TFR(6)  x0 += k0; x1 += k1 + 3u;
  TFR(17) TFR(29) TFR(16) TFR(24) x0 += k1; x1 += k2 + 4u;
  TFR(13) TFR(15) TFR(26) TFR(6)  x0 += k2; x1 += k0 + 5u;
  *o0 = x0; *o1 = x1;
#undef TFR
#undef TFROT
}

__device__ inline bool tf_keep(uint32_t ka, uint32_t kb, uint32_t idx) {
#if BITS_MODE == 0
  uint32_t a, b; tf2x32(ka, kb, 0u, idx, &a, &b);
  return (((a ^ b) >> 31) == 0u);      // partitionable x32: bits = o0 ^ o1
#else
  const uint32_t HALF = MSIZE / 2u;
  uint32_t a, b;
  if (idx < HALF) { tf2x32(ka, kb, idx, idx + HALF, &a, &b); return ((a >> 31) == 0u); }
  else            { tf2x32(ka, kb, idx - HALF, idx, &a, &b); return ((b >> 31) == 0u); }
#endif
}

__device__ inline float sigf(float x) { return 1.f / (1.f + __expf(-x)); }

// ---------------- workspace layout (floats) ----------------
static const size_t OFF_PM   = 0;                                    // 64*200*128
static const size_t OFF_XS   = OFF_PM   + (size_t)B_ * TIN * ATTD;   // 64*256
static const size_t OFF_HATT = OFF_XS   + (size_t)B_ * PRE;
static const size_t OFF_CATT = OFF_HATT + (size_t)B_ * RNN;
static const size_t OFF_HDEC = OFF_CATT + (size_t)B_ * RNN;
static const size_t OFF_CDEC = OFF_HDEC + (size_t)B_ * RNN;
static const size_t OFF_CTX  = OFF_CDEC + (size_t)B_ * RNN;
static const size_t OFF_AW   = OFF_CTX  + (size_t)B_ * ENC;
static const size_t OFF_AWC  = OFF_AW   + (size_t)B_ * TIN;
static const size_t OFF_PART = OFF_AWC  + (size_t)B_ * TIN;          // 8*64*4096

// ---------------- LDS union (max 61.4 KB) ----------------
union SM {
  struct { float xin[64 * 68]; float w[64 * WSTR]; } g;
  struct {
    float h[RNN]; float awp[TIN]; float awcp[TIN]; float loc[LOCF * TIN];
    float pq[ATTD]; float e4[4 * TIN]; float red[512];
    float wl[ATTD * LOCF]; float wc[LOCF * 2 * LOCK];
  } a;
  struct { float dha[RNN + ENC]; float red[512]; float inm[NMEL]; float h2[PRE]; } o;
};

struct Params {
  const float *memory, *dec, *w1, *w2;
  const float *wih_att, *whh_att, *bih_att, *bhh_att;
  const float *wq, *wv, *wconv, *wloc;
  const float *wih_dec, *whh_dec, *bih_dec, *bhh_dec;
  const float *wproj, *bproj, *wgate, *bgate;
  const int* mlen;
  float *out, *out_align, *pm, *xs, *hatt, *catt, *hdec, *cdec, *ctx, *aw, *awc, *part;
  uint32_t k1a, k1b, k2a, k2b;
};

// ---------------- pre-kernels ----------------
__global__ __launch_bounds__(256) void k_init(float* s, int n) {
  int i = blockIdx.x * 256 + threadIdx.x;
  if (i < n) s[i] = 0.f;
}

__global__ __launch_bounds__(128) void k_procmem(const float* __restrict__ memory,
    const float* __restrict__ wmem, float* __restrict__ pm) {
  int b = blockIdx.x / TIN, tt = blockIdx.x % TIN;
  int d = threadIdx.x;
  __shared__ __align__(16) float m_s[ENC];
  for (int k = d; k < ENC; k += 128) m_s[k] = memory[((size_t)b * TIN + tt) * ENC + k];
  __syncthreads();
  float a = 0.f;
  const float4* w4 = (const float4*)(wmem + (size_t)d * ENC);
  const float4* m4 = (const float4*)m_s;
  #pragma unroll 8
  for (int k = 0; k < ENC / 4; ++k) {
    float4 w = w4[k], v = m4[k];
    a += w.x * v.x + w.y * v.y + w.z * v.z + w.w * v.w;
  }
  pm[((size_t)b * TIN + tt) * ATTD + d] = a;
}

// ---------------- phase device functions ----------------
__device__ void gates_phase(SM* sm, const float* in1, int L1, const float* in2, int L2,
    const float* in3, const float* wih, int wihK, const float* whh,
    float* part, int nch, int bid, int tid) {
  int ctile = bid & 31, ks = bid >> 5;   // 32 ctiles x 8 ksplits
  int cg = tid & 31, bg = tid >> 5;      // c0 = cg*4, b0 = bg*4
  float acc[4][4];
  #pragma unroll
  for (int i = 0; i < 4; ++i)
    #pragma unroll
    for (int j = 0; j < 4; ++j) acc[i][j] = 0.f;

  int c_begin = (ks * nch) >> 3, c_end = ((ks + 1) * nch) >> 3;
  for (int cc = c_begin; cc < c_end; ++cc) {
    int k0 = cc * 64;
    const float* src; int sl, so;
    if (k0 < L1)            { src = in1; sl = L1;   so = k0; }
    else if (k0 < L1 + L2)  { src = in2; sl = L2;   so = k0 - L1; }
    else                    { src = in3; sl = 1024; so = k0 - L1 - L2; }
    const float* wsrc; int wl, wo;
    if (k0 < wihK) { wsrc = wih; wl = wihK; wo = k0; }
    else           { wsrc = whh; wl = 1024; wo = k0 - wihK; }

    __syncthreads();
    #pragma unroll
    for (int i = 0; i < 8; ++i) {            // input 64k x 64b
      int idx = tid + 512 * i;
      int b = idx >> 6, kk = idx & 63;
      sm->g.xin[kk * 68 + b] = src[(size_t)b * sl + so + kk];
    }
    #pragma unroll
    for (int i = 0; i < 4; ++i) {            // weights 128c x 64k via float4
      int idx = tid + 512 * i;
      int c = idx >> 4, kq = idx & 15;
      float4 w = *(const float4*)&wsrc[(size_t)(ctile * 128 + c) * wl + wo + kq * 4];
      sm->g.w[(kq * 4 + 0) * WSTR + c] = w.x;
      sm->g.w[(kq * 4 + 1) * WSTR + c] = w.y;
      sm->g.w[(kq * 4 + 2) * WSTR + c] = w.z;
      sm->g.w[(kq * 4 + 3) * WSTR + c] = w.w;
    }
    __syncthreads();
    #pragma unroll 4
    for (int kk = 0; kk < 64; ++kk) {
      float4 w = *(const float4*)&sm->g.w[kk * WSTR + cg * 4];
      float4 x = *(const float4*)&sm->g.xin[kk * 68 + bg * 4];
      float xr[4] = {x.x, x.y, x.z, x.w};
      float wr[4] = {w.x, w.y, w.z, w.w};
      #pragma unroll
      for (int i = 0; i < 4; ++i)
        #pragma unroll
        for (int j = 0; j < 4; ++j) acc[i][j] += xr[i] * wr[j];
    }
  }
  #pragma unroll
  for (int i = 0; i < 4; ++i) {
    float* dst = part + ((size_t)ks * B_ + (bg * 4 + i)) * G4 + ctile * 128 + cg * 4;
    *(float4*)dst = make_float4(acc[i][0], acc[i][1], acc[i][2], acc[i][3]);
  }
}

__device__ void attention_phase(SM* sm, const Params& p, int b, int tid, int t) {
  for (int k = tid; k < ATTD * LOCF; k += 512) sm->a.wl[k] = p.wloc[k];
  for (int k = tid; k < LOCF * 2 * LOCK; k += 512) sm->a.wc[k] = p.wconv[k];

  #pragma unroll
  for (int r = 0; r < 2; ++r) {
    int j = tid + 512 * r;
    float ig = p.bih_att[j] + p.bhh_att[j];
    float fg = p.bih_att[RNN + j] + p.bhh_att[RNN + j];
    float gg = p.bih_att[2 * RNN + j] + p.bhh_att[2 * RNN + j];
    float og = p.bih_att[3 * RNN + j] + p.bhh_att[3 * RNN + j];
    #pragma unroll
    for (int ks = 0; ks < KSPLIT; ++ks) {
      const float* pr = p.part + ((size_t)ks * B_ + b) * G4;
      ig += pr[j]; fg += pr[RNN + j]; gg += pr[2 * RNN + j]; og += pr[3 * RNN + j];
    }
    float c = sigf(fg) * p.catt[(size_t)b * RNN + j] + sigf(ig) * tanhf(gg);
    float h = sigf(og) * tanhf(c);
    p.catt[(size_t)b * RNN + j] = c;
    p.hatt[(size_t)b * RNN + j] = h;
    sm->a.h[j] = h;
  }
  for (int k = tid; k < TIN; k += 512) {
    sm->a.awp[k] = p.aw[(size_t)b * TIN + k];
    sm->a.awcp[k] = p.awc[(size_t)b * TIN + k];
  }
  __syncthreads();

  // pq = h @ wq.T (4-way K split)
  {
    int d = tid & 127, hf = tid >> 7;
    float a = 0.f;
    const float* wr = p.wq + (size_t)d * RNN + hf * 256;
    const float* hr = sm->a.h + hf * 256;
    #pragma unroll 8
    for (int k = 0; k < 256; ++k) a += hr[k] * wr[k];
    sm->a.red[tid] = a;
  }
  __syncthreads();
  if (tid < ATTD)
    sm->a.pq[tid] = sm->a.red[tid] + sm->a.red[tid + 128] + sm->a.red[tid + 256] + sm->a.red[tid + 384];

  // location conv
  for (int task = tid; task < LOCF * TIN; task += 512) {
    int f = task / TIN, tt = task % TIN;
    float a = 0.f;
    #pragma unroll
    for (int k = 0; k < LOCK; ++k) {
      int s = tt + k - 15;
      if (s >= 0 && s < TIN)
        a += sm->a.awp[s] * sm->a.wc[f * (2 * LOCK) + k] + sm->a.awcp[s] * sm->a.wc[f * (2 * LOCK) + LOCK + k];
    }
    sm->a.loc[task] = a;
  }
  __syncthreads();

  // energies, 4-way split over d
  for (int task = tid; task < 4 * TIN; task += 512) {
    int hf = task / TIN, tt = task - hf * TIN;
    float acc = 0.f;
    const float* pmr = p.pm + ((size_t)b * TIN + tt) * ATTD;
    #pragma unroll 4
    for (int d = hf * 32; d < hf * 32 + 32; ++d) {
      float pl = 0.f;
      #pragma unroll
      for (int f = 0; f < LOCF; ++f) pl += sm->a.loc[f * TIN + tt] * sm->a.wl[d * LOCF + f];
      acc += tanhf(pmr[d] + sm->a.pq[d] + pl) * p.wv[d];
    }
    sm->a.e4[task] = acc;
  }
  __syncthreads();

  // masked softmax over tt
  int len = p.mlen[b];
  float ev = -3.0e38f;
  if (tid < TIN)
    ev = (tid < len) ? (sm->a.e4[tid] + sm->a.e4[TIN + tid] + sm->a.e4[2 * TIN + tid] + sm->a.e4[3 * TIN + tid])
                     : -1.0e9f;
  sm->a.red[tid] = ev;
  __syncthreads();
  for (int s = 256; s > 0; s >>= 1) {
    if (tid < s) sm->a.red[tid] = fmaxf(sm->a.red[tid], sm->a.red[tid + s]);
    __syncthreads();
  }
  float m = sm->a.red[0];
  __syncthreads();
  float pr = (tid < TIN) ? __expf(ev - m) : 0.f;
  sm->a.red[tid] = pr;
  __syncthreads();
  for (int s = 256; s > 0; s >>= 1) {
    if (tid < s) sm->a.red[tid] += sm->a.red[tid + s];
    __syncthreads();
  }
  float inv = 1.f / sm->a.red[0];
  __syncthreads();
  if (tid < TIN) {
    float a = pr * inv;
    p.aw[(size_t)b * TIN + tid] = a;
    p.awc[(size_t)b * TIN + tid] = sm->a.awcp[tid] + a;
    p.out_align[((size_t)b * TOUT + t) * TIN + tid] = a;
    sm->a.awp[tid] = a;
  }
  __syncthreads();

  // ctx: one ee per thread (512 == ENC)
  {
    float a = 0.f;
    const float* mr = p.memory + (size_t)b * TIN * ENC + tid;
    #pragma unroll 8
    for (int tt = 0; tt < TIN; ++tt) a += sm->a.awp[tt] * mr[(size_t)tt * ENC];
    p.ctx[(size_t)b * ENC + tid] = a;
  }
}

__device__ void outphase_phase(SM* sm, const Params& p, int b, int tid, int t) {
  #pragma unroll
  for (int r = 0; r < 2; ++r) {
    int j = tid + 512 * r;
    float ig = p.bih_dec[j] + p.bhh_dec[j];
    float fg = p.bih_dec[RNN + j] + p.bhh_dec[RNN + j];
    float gg = p.bih_dec[2 * RNN + j] + p.bhh_dec[2 * RNN + j];
    float og = p.bih_dec[3 * RNN + j] + p.bhh_dec[3 * RNN + j];
    #pragma unroll
    for (int ks = 0; ks < KSPLIT; ++ks) {
      const float* pr = p.part + ((size_t)ks * B_ + b) * G4;
      ig += pr[j]; fg += pr[RNN + j]; gg += pr[2 * RNN + j]; og += pr[3 * RNN + j];
    }
    float c = sigf(fg) * p.cdec[(size_t)b * RNN + j] + sigf(ig) * tanhf(gg);
    float h = sigf(og) * tanhf(c);
    p.cdec[(size_t)b * RNN + j] = c;
    p.hdec[(size_t)b * RNN + j] = h;
    sm->o.dha[j] = h;
  }
  for (int k = tid; k < ENC; k += 512) sm->o.dha[RNN + k] = p.ctx[(size_t)b * ENC + k];
  if (t + 1 < TOUT && tid < NMEL)
    sm->o.inm[tid] = p.dec[((size_t)b * NMEL + tid) * TOUT + t];
  __syncthreads();

  // mel: 320 tasks (m, K-quarter of 384)
  float mp = 0.f;
  if (tid < 4 * NMEL) {
    int m = tid % NMEL, hf = tid / NMEL;
    const float* wr = p.wproj + (size_t)m * (RNN + ENC) + hf * 384;
    const float* dr = sm->o.dha + hf * 384;
    #pragma unroll 8
    for (int k = 0; k < 384; ++k) mp += dr[k] * wr[k];
  }
  sm->o.red[tid] = mp;
  __syncthreads();
  if (tid < NMEL) {
    float mel = sm->o.red[tid] + sm->o.red[tid + NMEL] + sm->o.red[tid + 2 * NMEL]
              + sm->o.red[tid + 3 * NMEL] + p.bproj[tid];
    p.out[((size_t)b * NMEL + tid) * TOUT + t] = mel;
  }
  __syncthreads();
  float g = 0.f;
  for (int k = tid; k < RNN + ENC; k += 512) g += sm->o.dha[k] * p.wgate[k];
  sm->o.red[tid] = g;
  __syncthreads();
  for (int s = 256; s > 0; s >>= 1) {
    if (tid < s) sm->o.red[tid] += sm->o.red[tid + s];
    __syncthreads();
  }
  if (tid == 0) p.out[(size_t)2048000 + (size_t)b * TOUT + t] = sm->o.red[0] + p.bgate[0];

  // prenet for step t+1
  if (t + 1 < TOUT) {
    int tn = t + 1;
    if (tid < PRE) {
      float a = 0.f;
      const float4* w14 = (const float4*)(p.w1 + (size_t)tid * NMEL);
      const float4* i4  = (const float4*)sm->o.inm;
      #pragma unroll
      for (int k = 0; k < NMEL / 4; ++k) {
        float4 w = w14[k], v = i4[k];
        a += w.x * v.x + w.y * v.y + w.z * v.z + w.w * v.w;
      }
      a = fmaxf(a, 0.f);
      uint32_t idx = (uint32_t)((tn * 64 + b) * 256 + tid);
      a = tf_keep(p.k1a, p.k1b, idx) ? a * 2.f : 0.f;
      sm->o.h2[tid] = a;
    }
    __syncthreads();
    if (tid < PRE) {
      float a2 = 0.f;
      const float4* w24 = (const float4*)(p.w2 + (size_t)tid * PRE);
      const float4* h4  = (const float4*)sm->o.h2;
      #pragma unroll 8
      for (int k = 0; k < PRE / 4; ++k) {
        float4 w = w24[k], v = h4[k];
        a2 += w.x * v.x + w.y * v.y + w.z * v.z + w.w * v.w;
      }
      a2 = fmaxf(a2, 0.f);
      uint32_t idx = (uint32_t)((tn * 64 + b) * 256 + tid);
      a2 = tf_keep(p.k2a, p.k2b, idx) ? a2 * 2.f : 0.f;
      p.xs[((size_t)b << 8) + tid] = a2;
    }
  }
}

// ---------------- the persistent cooperative kernel ----------------
__global__ __launch_bounds__(512) void k_persist(Params p) {
  cg::grid_group grid = cg::this_grid();
  int bid = blockIdx.x, tid = threadIdx.x;
  __shared__ __align__(16) SM sm;

  for (int t = 0; t < TOUT; ++t) {
    // A: att gates  K = [xs(256) | ctx(512) | hatt(1024)], wihK=768, 28 chunks
    gates_phase(&sm, p.xs, PRE, p.ctx, ENC, p.hatt, p.wih_att, PRE + ENC, p.whh_att,
                p.part, 28, bid, tid);
    __threadfence();
    grid.sync();

    // B: attention (blocks 0..63)
    if (bid < B_) attention_phase(&sm, p, bid, tid, t);
    __threadfence();
    grid.sync();

    // C: dec gates  K = [hatt(1024) | ctx(512) | hdec(1024)], wihK=1536, 40 chunks
    gates_phase(&sm, p.hatt, RNN, p.ctx, ENC, p.hdec, p.wih_dec, RNN + ENC, p.whh_dec,
                p.part, 40, bid, tid);
    __threadfence();
    grid.sync();

    // D: outphase + prenet(t+1) (blocks 0..63)
    if (bid < B_) outphase_phase(&sm, p, bid, tid, t);
    __threadfence();
    grid.sync();
  }
}

// ---------------- host launcher ----------------
extern "C" void kernel_launch(void* const* d_in, const int* in_sizes, int n_in,
                              void* d_out, int out_size, void* d_ws, size_t ws_size,
                              hipStream_t stream) {
  (void)in_sizes; (void)n_in; (void)out_size; (void)ws_size;
  const float* memory  = (const float*)d_in[0];
  const float* dec     = (const float*)d_in[1];
  const int*   mlen    = (const int*)d_in[2];
  const float* w1      = (const float*)d_in[3];
  const float* w2      = (const float*)d_in[4];
  const float* wih_att = (const float*)d_in[5];
  const float* whh_att = (const float*)d_in[6];
  const float* bih_att = (const float*)d_in[7];
  const float* bhh_att = (const float*)d_in[8];
  const float* wq      = (const float*)d_in[9];
  const float* wmem    = (const float*)d_in[10];
  const float* wv      = (const float*)d_in[11];
  const float* wconv   = (const float*)d_in[12];
  const float* wloc    = (const float*)d_in[13];
  const float* wih_dec = (const float*)d_in[14];
  const float* whh_dec = (const float*)d_in[15];
  const float* bih_dec = (const float*)d_in[16];
  const float* bhh_dec = (const float*)d_in[17];
  const float* wproj   = (const float*)d_in[18];
  const float* bproj   = (const float*)d_in[19];
  const float* wgate   = (const float*)d_in[20];
  const float* bgate   = (const float*)d_in[21];
  float* out = (float*)d_out;
  float* ws  = (float*)d_ws;

  // dropout keys from jax.random.split(jax.random.key(42)); key = (0, 42)
  uint32_t dk1a, dk1b, dk2a, dk2b;
#if SPLIT_MODE == 0
  tf2x32(0u, 42u, 0u, 0u, &dk1a, &dk1b);
  tf2x32(0u, 42u, 0u, 1u, &dk2a, &dk2b);
#else
  uint32_t a0, b0, a1, b1;
  tf2x32(0u, 42u, 0u, 2u, &a0, &b0);
  tf2x32(0u, 42u, 1u, 3u, &a1, &b1);
  dk1a = a0; dk1b = a1; dk2a = b0; dk2b = b1;
#endif

  float* pm   = ws + OFF_PM;
  float* xs   = ws + OFF_XS;
  float* hatt = ws + OFF_HATT; float* catt = ws + OFF_CATT;
  float* hdec = ws + OFF_HDEC; float* cdec = ws + OFF_CDEC;
  float* ctxp = ws + OFF_CTX;
  float* aw   = ws + OFF_AW;   float* awc  = ws + OFF_AWC;
  float* part = ws + OFF_PART;

  int nstate = B_ * (PRE + 4 * RNN + ENC + 2 * TIN);   // xs..awc contiguous (xs=0 == x_0)
  k_init<<<(nstate + 255) / 256, 256, 0, stream>>>(xs, nstate);
  k_procmem<<<B_ * TIN, 128, 0, stream>>>(memory, wmem, pm);

  Params p;
  p.memory = memory; p.dec = dec; p.w1 = w1; p.w2 = w2;
  p.wih_att = wih_att; p.whh_att = whh_att; p.bih_att = bih_att; p.bhh_att = bhh_att;
  p.wq = wq; p.wv = wv; p.wconv = wconv; p.wloc = wloc;
  p.wih_dec = wih_dec; p.whh_dec = whh_dec; p.bih_dec = bih_dec; p.bhh_dec = bhh_dec;
  p.wproj = wproj; p.bproj = bproj; p.wgate = wgate; p.bgate = bgate;
  p.mlen = mlen;
  p.out = out; p.out_align = out + 2073600;
  p.pm = pm; p.xs = xs; p.hatt = hatt; p.catt = catt; p.hdec = hdec; p.cdec = cdec;
  p.ctx = ctxp; p.aw = aw; p.awc = awc; p.part = part;
  p.k1a = dk1a; p.k1b = dk1b; p.k2a = dk2a; p.k2b = dk2b;

  void* args[] = { &p };
  hipLaunchCooperativeKernel((const void*)k_persist, dim3(256), dim3(512), args, 0, stream);
}